// Round 16
// baseline (280.706 us; speedup 1.0000x reference)
//
#include <hip/hip_runtime.h>

// Problem constants: N=8, T=256, H=8, KQ=128, V=32
#define N_ 8
#define T_ 256
#define H_ 8
#define KQ_ 128
#define V_ 32

typedef float f32x4 __attribute__((ext_vector_type(4)));

// ---------------------------------------------------------------------------
// Phase 1 v5 (frozen from R12): tiled-GEMM projections, dst[n][h][d][t].
// grid: 256 = proj(2)*n(8)*h(8)*dh(2), 256 thr
// ---------------------------------------------------------------------------
__global__ __launch_bounds__(256) void proj_kernel(
    const float* __restrict__ query, const float* __restrict__ key,
    const float* __restrict__ Wq, const float* __restrict__ bq,
    const float* __restrict__ Wk, const float* __restrict__ bk,
    float* __restrict__ hqT, float* __restrict__ hkT)
{
  int b = blockIdx.x;
  int dh = b & 1;
  int h  = (b >> 1) & 7;
  int n  = (b >> 4) & 7;
  int proj = (b >> 7) & 1;
  const float* src  = proj ? key : query;
  const float* W    = proj ? Wk  : Wq;
  const float* bias = proj ? bk  : bq;
  float* dst        = proj ? hkT : hqT;
  int d0 = dh * 64;

  __shared__ float qs[256 * 36];
  __shared__ float ws[64 * 36];

  int tl   = threadIdx.x & 31;
  int dsub = threadIdx.x >> 5;
  const float* qsrc = src + (size_t)n * T_ * KQ_;
  const float* wsrc = W + (size_t)(h * KQ_ + d0) * KQ_;

  float acc[8][8];
#pragma unroll
  for (int it = 0; it < 8; ++it)
#pragma unroll
    for (int dd = 0; dd < 8; ++dd) acc[it][dd] = 0.f;

  for (int kc = 0; kc < 4; ++kc) {
    if (kc) __syncthreads();
    {
      int r = threadIdx.x >> 3, c4 = (threadIdx.x & 7) * 4;
#pragma unroll
      for (int rep = 0; rep < 8; ++rep) {
        int row = r + rep * 32;
        *(float4*)&qs[row * 36 + c4] =
            *(const float4*)&qsrc[(size_t)row * KQ_ + kc * 32 + c4];
      }
#pragma unroll
      for (int rep = 0; rep < 2; ++rep) {
        int row = r + rep * 32;
        *(float4*)&ws[row * 36 + c4] =
            *(const float4*)&wsrc[(size_t)row * KQ_ + kc * 32 + c4];
      }
    }
    __syncthreads();

#pragma unroll 2
    for (int j0 = 0; j0 < 32; j0 += 4) {
      float4 qv[8];
#pragma unroll
      for (int it = 0; it < 8; ++it)
        qv[it] = *(const float4*)&qs[(tl + 32 * it) * 36 + j0];
#pragma unroll
      for (int dd = 0; dd < 8; ++dd) {
        float4 w4 = *(const float4*)&ws[(dsub * 8 + dd) * 36 + j0];
#pragma unroll
        for (int it = 0; it < 8; ++it) {
          acc[it][dd] = fmaf(qv[it].x, w4.x, acc[it][dd]);
          acc[it][dd] = fmaf(qv[it].y, w4.y, acc[it][dd]);
          acc[it][dd] = fmaf(qv[it].z, w4.z, acc[it][dd]);
          acc[it][dd] = fmaf(qv[it].w, w4.w, acc[it][dd]);
        }
      }
    }
  }

#pragma unroll
  for (int dd = 0; dd < 8; ++dd) {
    int d = d0 + dsub * 8 + dd;
    float bb = bias[h * KQ_ + d];
    size_t base = (((size_t)n * H_ + h) * KQ_ + d) * T_;
#pragma unroll
    for (int it = 0; it < 8; ++it)
      dst[base + it * 32 + tl] = acc[it][dd] + bb;
  }
}

// ---------------------------------------------------------------------------
// Phase 2 FUSED (frozen from R13). Launched TWICE this round (idempotent):
// A = dur_us - 158 isolates this kernel's duration. Remove dup next round.
// grid: 2048 = n(8)*h(8)*qtile(32), 64 threads.
// ---------------------------------------------------------------------------
__global__ __launch_bounds__(64) void attn_kernel(
    const float* __restrict__ hqT, const float* __restrict__ hkT,
    const int* __restrict__ mask, const float* __restrict__ value,
    float* __restrict__ p_out, float* __restrict__ out_ws)
{
  const float SCALE = 0.08838834764831845f;   // 1/sqrt(128)
  int b = blockIdx.x;
  int q0 = (b & 31) * 8;
  int h  = (b >> 5) & 7;
  int n  = b >> 8;
  int l  = threadIdx.x;                        // 0..63, single wave
  int row0 = (n * H_ + h) * T_ + q0;

  __shared__ float hq_s[KQ_ * 12];   // [j][qq] pad 12
  __shared__ float e_s[T_ * 8];      // [k][qq]
  __shared__ float inv_s[8 * 32];    // [qq][v]

  const float* hqbase = hqT + ((size_t)n * H_ + h) * KQ_ * T_;
  const float* hkbase = hkT + ((size_t)n * H_ + h) * KQ_ * T_;

  // stage hq: 128j x 8q
#pragma unroll
  for (int rep = 0; rep < 16; ++rep) {
    int i = l + 64 * rep;
    int j = i >> 3, qq = i & 7;
    hq_s[j * 12 + qq] = hqbase[(size_t)j * T_ + q0 + qq];
  }
  __syncthreads();

  // scores: lane l covers k = l + 64i, i=0..3
  float acc[4][8];
#pragma unroll
  for (int i = 0; i < 4; ++i)
#pragma unroll
    for (int qq = 0; qq < 8; ++qq) acc[i][qq] = 0.f;

#pragma unroll 4
  for (int j = 0; j < KQ_; ++j) {
    float hk0 = hkbase[(size_t)j * T_ + l];
    float hk1 = hkbase[(size_t)j * T_ + l + 64];
    float hk2 = hkbase[(size_t)j * T_ + l + 128];
    float hk3 = hkbase[(size_t)j * T_ + l + 192];
    float4 a0 = *(const float4*)&hq_s[j * 12];       // wave-uniform broadcast
    float4 a1 = *(const float4*)&hq_s[j * 12 + 4];
    acc[0][0] = fmaf(a0.x, hk0, acc[0][0]); acc[0][1] = fmaf(a0.y, hk0, acc[0][1]);
    acc[0][2] = fmaf(a0.z, hk0, acc[0][2]); acc[0][3] = fmaf(a0.w, hk0, acc[0][3]);
    acc[0][4] = fmaf(a1.x, hk0, acc[0][4]); acc[0][5] = fmaf(a1.y, hk0, acc[0][5]);
    acc[0][6] = fmaf(a1.z, hk0, acc[0][6]); acc[0][7] = fmaf(a1.w, hk0, acc[0][7]);
    acc[1][0] = fmaf(a0.x, hk1, acc[1][0]); acc[1][1] = fmaf(a0.y, hk1, acc[1][1]);
    acc[1][2] = fmaf(a0.z, hk1, acc[1][2]); acc[1][3] = fmaf(a0.w, hk1, acc[1][3]);
    acc[1][4] = fmaf(a1.x, hk1, acc[1][4]); acc[1][5] = fmaf(a1.y, hk1, acc[1][5]);
    acc[1][6] = fmaf(a1.z, hk1, acc[1][6]); acc[1][7] = fmaf(a1.w, hk1, acc[1][7]);
    acc[2][0] = fmaf(a0.x, hk2, acc[2][0]); acc[2][1] = fmaf(a0.y, hk2, acc[2][1]);
    acc[2][2] = fmaf(a0.z, hk2, acc[2][2]); acc[2][3] = fmaf(a0.w, hk2, acc[2][3]);
    acc[2][4] = fmaf(a1.x, hk2, acc[2][4]); acc[2][5] = fmaf(a1.y, hk2, acc[2][5]);
    acc[2][6] = fmaf(a1.z, hk2, acc[2][6]); acc[2][7] = fmaf(a1.w, hk2, acc[2][7]);
    acc[3][0] = fmaf(a0.x, hk3, acc[3][0]); acc[3][1] = fmaf(a0.y, hk3, acc[3][1]);
    acc[3][2] = fmaf(a0.z, hk3, acc[3][2]); acc[3][3] = fmaf(a0.w, hk3, acc[3][3]);
    acc[3][4] = fmaf(a1.x, hk3, acc[3][4]); acc[3][5] = fmaf(a1.y, hk3, acc[3][5]);
    acc[3][6] = fmaf(a1.z, hk3, acc[3][6]); acc[3][7] = fmaf(a1.w, hk3, acc[3][7]);
  }

  // softmax numerators -> e_s
  {
#pragma unroll
    for (int qq = 0; qq < 8; ++qq) {
      float m = fmaxf(fmaxf(acc[0][qq] * SCALE, acc[1][qq] * SCALE),
                      fmaxf(acc[2][qq] * SCALE, acc[3][qq] * SCALE));
      for (int off = 32; off >= 1; off >>= 1)
        m = fmaxf(m, __shfl_xor(m, off, 64));
#pragma unroll
      for (int i = 0; i < 4; ++i)
        acc[i][qq] = __expf(acc[i][qq] * SCALE - m);
    }
  }
#pragma unroll
  for (int i = 0; i < 4; ++i) {
    int k = l + 64 * i;
    *(f32x4*)&e_s[k * 8]     = f32x4{acc[i][0], acc[i][1], acc[i][2], acc[i][3]};
    *(f32x4*)&e_s[k * 8 + 4] = f32x4{acc[i][4], acc[i][5], acc[i][6], acc[i][7]};
  }
  __syncthreads();

  // denominators + PV
  const int*   mrow = mask  + (size_t)n * T_ * V_;
  const float* vrow = value + (size_t)n * T_ * V_;
  int v = l & 31, kh = l >> 5;
  float s8[8], o8[8];
#pragma unroll
  for (int qq = 0; qq < 8; ++qq) { s8[qq] = 0.f; o8[qq] = 0.f; }
#pragma unroll 4
  for (int i = 0; i < 128; ++i) {
    int k = kh * 128 + i;
    float mf = (float)mrow[k * V_ + v];
    float vv = vrow[k * V_ + v];
    float4 e0 = *(const float4*)&e_s[k * 8];
    float4 e1 = *(const float4*)&e_s[k * 8 + 4];
    float p;
    p = e0.x * mf; s8[0] += p; o8[0] = fmaf(p, vv, o8[0]);
    p = e0.y * mf; s8[1] += p; o8[1] = fmaf(p, vv, o8[1]);
    p = e0.z * mf; s8[2] += p; o8[2] = fmaf(p, vv, o8[2]);
    p = e0.w * mf; s8[3] += p; o8[3] = fmaf(p, vv, o8[3]);
    p = e1.x * mf; s8[4] += p; o8[4] = fmaf(p, vv, o8[4]);
    p = e1.y * mf; s8[5] += p; o8[5] = fmaf(p, vv, o8[5]);
    p = e1.z * mf; s8[6] += p; o8[6] = fmaf(p, vv, o8[6]);
    p = e1.w * mf; s8[7] += p; o8[7] = fmaf(p, vv, o8[7]);
  }
#pragma unroll
  for (int qq = 0; qq < 8; ++qq) {
    s8[qq] += __shfl_xor(s8[qq], 32, 64);
    o8[qq] += __shfl_xor(o8[qq], 32, 64);
  }
  if (kh == 0) {
#pragma unroll
    for (int qq = 0; qq < 8; ++qq) {
      float inv = 1.0f / s8[qq];
      inv_s[qq * 32 + v] = inv;
      out_ws[(((size_t)n * T_ + q0 + qq) * H_ + h) * V_ + v] = o8[qq] * inv;
    }
  }
  __syncthreads();

  // direct p_attn streaming: 8 rows x 2048 f32x4, NT stores, coalesced per qq
  {
    int v0 = (l & 7) * 4;
    f32x4 iv[8];
#pragma unroll
    for (int qq = 0; qq < 8; ++qq)
      iv[qq] = *(const f32x4*)&inv_s[qq * 32 + v0];
    f32x4* pbase = (f32x4*)p_out + (size_t)row0 * 2048;

#pragma unroll 4
    for (int rep = 0; rep < 32; ++rep) {
      int e4 = rep * 64 + l;
      int k  = rep * 8 + (l >> 3);
      const int4 m4 = *(const int4*)&mrow[k * V_ + v0];
      float fx = (float)m4.x, fy = (float)m4.y, fz = (float)m4.z, fw = (float)m4.w;
      f32x4 e0 = *(const f32x4*)&e_s[k * 8];
      f32x4 e1 = *(const f32x4*)&e_s[k * 8 + 4];
      float e[8] = {e0.x, e0.y, e0.z, e0.w, e1.x, e1.y, e1.z, e1.w};
#pragma unroll
      for (int qq = 0; qq < 8; ++qq) {
        f32x4 pv;
        pv.x = e[qq] * fx * iv[qq].x;
        pv.y = e[qq] * fy * iv[qq].y;
        pv.z = e[qq] * fz * iv[qq].z;
        pv.w = e[qq] * fw * iv[qq].w;
        __builtin_nontemporal_store(pv, &pbase[(size_t)qq * 2048 + e4]);
      }
    }
  }
}

// ---------------------------------------------------------------------------
// Phase 3 v2 (frozen from R8)
// ---------------------------------------------------------------------------
__global__ __launch_bounds__(256) void outproj_kernel(
    const float* __restrict__ out_ws, const float* __restrict__ Wo,
    const float* __restrict__ bo, float* __restrict__ out_rep)
{
  __shared__ float wot[256 * 33];
  __shared__ float rows_s[4 * 256];
  __shared__ float red[4 * 32];
  int r0 = blockIdx.x * 4;
  for (int i = threadIdx.x; i < 32 * 256; i += 256) {
    int o = i >> 8, c = i & 255;
    wot[c * 33 + o] = Wo[i];
  }
  for (int i = threadIdx.x; i < 4 * 256; i += 256)
    rows_s[i] = out_ws[(size_t)r0 * 256 + i];
  __syncthreads();
  int o  = threadIdx.x & 31;
  int rr = (threadIdx.x >> 5) & 3;
  int kh = threadIdx.x >> 7;
  int cb = kh * 128;
  float acc = 0.f;
#pragma unroll 4
  for (int c = 0; c < 128; ++c)
    acc = fmaf(rows_s[rr * 256 + cb + c], wot[(cb + c) * 33 + o], acc);
  if (kh == 1) red[rr * 32 + o] = acc;
  __syncthreads();
  if (kh == 0)
    out_rep[(size_t)(r0 + rr) * 32 + o] = acc + red[rr * 32 + o] + bo[o];
}

// ---------------------------------------------------------------------------
extern "C" void kernel_launch(void* const* d_in, const int* in_sizes, int n_in,
                              void* d_out, int out_size, void* d_ws, size_t ws_size,
                              hipStream_t stream) {
  const float* value = (const float*)d_in[0];
  const float* key   = (const float*)d_in[1];
  const float* query = (const float*)d_in[2];
  const int*   mask  = (const int*)d_in[3];
  const float* Wq = (const float*)d_in[4];
  const float* bq = (const float*)d_in[5];
  const float* Wk = (const float*)d_in[6];
  const float* bk = (const float*)d_in[7];
  const float* Wo = (const float*)d_in[8];
  const float* bo = (const float*)d_in[9];

  float* out_rep = (float*)d_out;
  float* p_out   = (float*)d_out + (size_t)N_ * T_ * V_;

  float* hqT    = (float*)d_ws;
  float* hkT    = hqT + (size_t)N_ * H_ * KQ_ * T_;
  float* out_ws = hkT + (size_t)N_ * H_ * KQ_ * T_;

  hipLaunchKernelGGL(proj_kernel, dim3(256), dim3(256), 0, stream,
                     query, key, Wq, bq, Wk, bk, hqT, hkT);
  // DIAGNOSTIC: attn launched twice (idempotent). A = dur_us - 158 isolates
  // the fused kernel's duration. Remove the duplicate next round.
  hipLaunchKernelGGL(attn_kernel, dim3(2048), dim3(64), 0, stream,
                     hqT, hkT, mask, value, p_out, out_ws);
  hipLaunchKernelGGL(attn_kernel, dim3(2048), dim3(64), 0, stream,
                     hqT, hkT, mask, value, p_out, out_ws);
  hipLaunchKernelGGL(outproj_kernel, dim3(512), dim3(256), 0, stream,
                     out_ws, Wo, bo, out_rep);
}

// Round 19
// 163.274 us; speedup vs baseline: 1.7192x; 1.7192x over previous
//
#include <hip/hip_runtime.h>

// Problem constants: N=8, T=256, H=8, KQ=128, V=32
#define N_ 8
#define T_ 256
#define H_ 8
#define KQ_ 128
#define V_ 32

typedef float f32x4 __attribute__((ext_vector_type(4)));
typedef float f32x2 __attribute__((ext_vector_type(2)));

// ---------------------------------------------------------------------------
// Phase 1 v5 (frozen from R12): tiled-GEMM projections, dst[n][h][d][t].
// grid: 256 = proj(2)*n(8)*h(8)*dh(2), 256 thr
// ---------------------------------------------------------------------------
__global__ __launch_bounds__(256) void proj_kernel(
    const float* __restrict__ query, const float* __restrict__ key,
    const float* __restrict__ Wq, const float* __restrict__ bq,
    const float* __restrict__ Wk, const float* __restrict__ bk,
    float* __restrict__ hqT, float* __restrict__ hkT)
{
  int b = blockIdx.x;
  int dh = b & 1;
  int h  = (b >> 1) & 7;
  int n  = (b >> 4) & 7;
  int proj = (b >> 7) & 1;
  const float* src  = proj ? key : query;
  const float* W    = proj ? Wk  : Wq;
  const float* bias = proj ? bk  : bq;
  float* dst        = proj ? hkT : hqT;
  int d0 = dh * 64;

  __shared__ float qs[256 * 36];
  __shared__ float ws[64 * 36];

  int tl   = threadIdx.x & 31;
  int dsub = threadIdx.x >> 5;
  const float* qsrc = src + (size_t)n * T_ * KQ_;
  const float* wsrc = W + (size_t)(h * KQ_ + d0) * KQ_;

  float acc[8][8];
#pragma unroll
  for (int it = 0; it < 8; ++it)
#pragma unroll
    for (int dd = 0; dd < 8; ++dd) acc[it][dd] = 0.f;

  for (int kc = 0; kc < 4; ++kc) {
    if (kc) __syncthreads();
    {
      int r = threadIdx.x >> 3, c4 = (threadIdx.x & 7) * 4;
#pragma unroll
      for (int rep = 0; rep < 8; ++rep) {
        int row = r + rep * 32;
        *(float4*)&qs[row * 36 + c4] =
            *(const float4*)&qsrc[(size_t)row * KQ_ + kc * 32 + c4];
      }
#pragma unroll
      for (int rep = 0; rep < 2; ++rep) {
        int row = r + rep * 32;
        *(float4*)&ws[row * 36 + c4] =
            *(const float4*)&wsrc[(size_t)row * KQ_ + kc * 32 + c4];
      }
    }
    __syncthreads();

#pragma unroll 2
    for (int j0 = 0; j0 < 32; j0 += 4) {
      float4 qv[8];
#pragma unroll
      for (int it = 0; it < 8; ++it)
        qv[it] = *(const float4*)&qs[(tl + 32 * it) * 36 + j0];
#pragma unroll
      for (int dd = 0; dd < 8; ++dd) {
        float4 w4 = *(const float4*)&ws[(dsub * 8 + dd) * 36 + j0];
#pragma unroll
        for (int it = 0; it < 8; ++it) {
          acc[it][dd] = fmaf(qv[it].x, w4.x, acc[it][dd]);
          acc[it][dd] = fmaf(qv[it].y, w4.y, acc[it][dd]);
          acc[it][dd] = fmaf(qv[it].z, w4.z, acc[it][dd]);
          acc[it][dd] = fmaf(qv[it].w, w4.w, acc[it][dd]);
        }
      }
    }
  }

#pragma unroll
  for (int dd = 0; dd < 8; ++dd) {
    int d = d0 + dsub * 8 + dd;
    float bb = bias[h * KQ_ + d];
    size_t base = (((size_t)n * H_ + h) * KQ_ + d) * T_;
#pragma unroll
    for (int it = 0; it < 8; ++it)
      dst[base + it * 32 + tl] = acc[it][dd] + bb;
  }
}

// ---------------------------------------------------------------------------
// Phase 2 FUSED v2 (R17, second resubmit): 2-q tiles, 8192 blocks x 64 thr.
// R16 measured fused v1 = 123us vs 81us store floor: compute wall (42us,
// 512 scalar hk loads/lane, 1 residency round) serialized with store wall.
// v2: k=4*lane+i -> float4 hk loads (128 VMEM/lane); tiny tiles (~3KB LDS,
// small VGPR) -> many blocks/CU, natural stagger/rounds so compute
// overlaps store drain.
// grid: 8192 = n(8)*h(8)*qtile(128 of 2q), 64 threads.
// ---------------------------------------------------------------------------
__global__ __launch_bounds__(64) void attn_kernel(
    const float* __restrict__ hqT, const float* __restrict__ hkT,
    const int* __restrict__ mask, const float* __restrict__ value,
    float* __restrict__ p_out, float* __restrict__ out_ws)
{
  const float SCALE = 0.08838834764831845f;   // 1/sqrt(128)
  int b = blockIdx.x;
  int q0 = (b & 127) * 2;
  int h  = (b >> 7) & 7;
  int n  = b >> 10;
  int l  = threadIdx.x;                        // 0..63, single wave
  int row0 = (n * H_ + h) * T_ + q0;

  __shared__ float hq_s[KQ_ * 2];    // [j][qq] 1KB
  __shared__ float e_s[T_ * 2];      // [k][qq] 2KB
  __shared__ float inv_s[2 * 32];    // [qq][v]

  const float* hqbase = hqT + ((size_t)n * H_ + h) * KQ_ * T_;
  const float* hkbase = hkT + ((size_t)n * H_ + h) * KQ_ * T_;

  // stage hq: 128j x 2q (tiny; strided source, hot in L2)
#pragma unroll
  for (int rep = 0; rep < 4; ++rep) {
    int i = l + 64 * rep;
    hq_s[i] = hqbase[(size_t)(i >> 1) * T_ + q0 + (i & 1)];
  }
  __syncthreads();

  // scores: lane l covers k = 4l+i, i=0..3  -> float4 hk loads
  float acc[4][2];
#pragma unroll
  for (int i = 0; i < 4; ++i) { acc[i][0] = 0.f; acc[i][1] = 0.f; }

#pragma unroll 4
  for (int j = 0; j < KQ_; ++j) {
    float4 hk = *(const float4*)&hkbase[(size_t)j * T_ + 4 * l];  // coalesced
    f32x2 a = *(const f32x2*)&hq_s[j * 2];                        // broadcast
    acc[0][0] = fmaf(a.x, hk.x, acc[0][0]); acc[0][1] = fmaf(a.y, hk.x, acc[0][1]);
    acc[1][0] = fmaf(a.x, hk.y, acc[1][0]); acc[1][1] = fmaf(a.y, hk.y, acc[1][1]);
    acc[2][0] = fmaf(a.x, hk.z, acc[2][0]); acc[2][1] = fmaf(a.y, hk.z, acc[2][1]);
    acc[3][0] = fmaf(a.x, hk.w, acc[3][0]); acc[3][1] = fmaf(a.y, hk.w, acc[3][1]);
  }

  // softmax numerators -> e_s
#pragma unroll
  for (int qq = 0; qq < 2; ++qq) {
    float m = fmaxf(fmaxf(acc[0][qq], acc[1][qq]),
                    fmaxf(acc[2][qq], acc[3][qq])) * SCALE;
    for (int off = 32; off >= 1; off >>= 1)
      m = fmaxf(m, __shfl_xor(m, off, 64));
#pragma unroll
    for (int i = 0; i < 4; ++i)
      acc[i][qq] = __expf(acc[i][qq] * SCALE - m);
  }
#pragma unroll
  for (int i = 0; i < 4; ++i) {
    int k = 4 * l + i;
    *(f32x2*)&e_s[k * 2] = f32x2{acc[i][0], acc[i][1]};
  }
  __syncthreads();

  // denominators + PV: v = l&31, half-wave splits k; shfl_xor(32) combines
  const int*   mrow = mask  + (size_t)n * T_ * V_;
  const float* vrow = value + (size_t)n * T_ * V_;
  int v = l & 31, kh = l >> 5;
  float s2[2] = {0.f, 0.f}, o2[2] = {0.f, 0.f};
#pragma unroll 4
  for (int i = 0; i < 128; ++i) {
    int k = kh * 128 + i;
    float mf = (float)mrow[k * V_ + v];
    float vv = vrow[k * V_ + v];
    f32x2 e = *(const f32x2*)&e_s[k * 2];     // uniform per half-wave
    float p;
    p = e.x * mf; s2[0] += p; o2[0] = fmaf(p, vv, o2[0]);
    p = e.y * mf; s2[1] += p; o2[1] = fmaf(p, vv, o2[1]);
  }
#pragma unroll
  for (int qq = 0; qq < 2; ++qq) {
    s2[qq] += __shfl_xor(s2[qq], 32, 64);
    o2[qq] += __shfl_xor(o2[qq], 32, 64);
  }
  if (kh == 0) {
#pragma unroll
    for (int qq = 0; qq < 2; ++qq) {
      float inv = 1.0f / s2[qq];
      inv_s[qq * 32 + v] = inv;
      out_ws[(((size_t)n * T_ + q0 + qq) * H_ + h) * V_ + v] = o2[qq] * inv;
    }
  }
  __syncthreads();

  // direct p_attn streaming: 2 rows x 2048 f32x4, NT stores, coalesced
  {
    int v0 = (l & 7) * 4;
    f32x4 iv0 = *(const f32x4*)&inv_s[v0];
    f32x4 iv1 = *(const f32x4*)&inv_s[32 + v0];
    f32x4* pbase = (f32x4*)p_out + (size_t)row0 * 2048;

#pragma unroll 4
    for (int rep = 0; rep < 32; ++rep) {
      int e4 = rep * 64 + l;
      int k  = rep * 8 + (l >> 3);
      const int4 m4 = *(const int4*)&mrow[k * V_ + v0];
      float fx = (float)m4.x, fy = (float)m4.y, fz = (float)m4.z, fw = (float)m4.w;
      f32x2 e = *(const f32x2*)&e_s[k * 2];
      f32x4 pv0, pv1;
      pv0.x = e.x * fx * iv0.x; pv0.y = e.x * fy * iv0.y;
      pv0.z = e.x * fz * iv0.z; pv0.w = e.x * fw * iv0.w;
      pv1.x = e.y * fx * iv1.x; pv1.y = e.y * fy * iv1.y;
      pv1.z = e.y * fz * iv1.z; pv1.w = e.y * fw * iv1.w;
      __builtin_nontemporal_store(pv0, &pbase[e4]);
      __builtin_nontemporal_store(pv1, &pbase[2048 + e4]);
    }
  }
}

// ---------------------------------------------------------------------------
// Phase 3 v2 (frozen from R8)
// ---------------------------------------------------------------------------
__global__ __launch_bounds__(256) void outproj_kernel(
    const float* __restrict__ out_ws, const float* __restrict__ Wo,
    const float* __restrict__ bo, float* __restrict__ out_rep)
{
  __shared__ float wot[256 * 33];
  __shared__ float rows_s[4 * 256];
  __shared__ float red[4 * 32];
  int r0 = blockIdx.x * 4;
  for (int i = threadIdx.x; i < 32 * 256; i += 256) {
    int o = i >> 8, c = i & 255;
    wot[c * 33 + o] = Wo[i];
  }
  for (int i = threadIdx.x; i < 4 * 256; i += 256)
    rows_s[i] = out_ws[(size_t)r0 * 256 + i];
  __syncthreads();
  int o  = threadIdx.x & 31;
  int rr = (threadIdx.x >> 5) & 3;
  int kh = threadIdx.x >> 7;
  int cb = kh * 128;
  float acc = 0.f;
#pragma unroll 4
  for (int c = 0; c < 128; ++c)
    acc = fmaf(rows_s[rr * 256 + cb + c], wot[(cb + c) * 33 + o], acc);
  if (kh == 1) red[rr * 32 + o] = acc;
  __syncthreads();
  if (kh == 0)
    out_rep[(size_t)(r0 + rr) * 32 + o] = acc + red[rr * 32 + o] + bo[o];
}

// ---------------------------------------------------------------------------
extern "C" void kernel_launch(void* const* d_in, const int* in_sizes, int n_in,
                              void* d_out, int out_size, void* d_ws, size_t ws_size,
                              hipStream_t stream) {
  const float* value = (const float*)d_in[0];
  const float* key   = (const float*)d_in[1];
  const float* query = (const float*)d_in[2];
  const int*   mask  = (const int*)d_in[3];
  const float* Wq = (const float*)d_in[4];
  const float* bq = (const float*)d_in[5];
  const float* Wk = (const float*)d_in[6];
  const float* bk = (const float*)d_in[7];
  const float* Wo = (const float*)d_in[8];
  const float* bo = (const float*)d_in[9];

  float* out_rep = (float*)d_out;
  float* p_out   = (float*)d_out + (size_t)N_ * T_ * V_;

  float* hqT    = (float*)d_ws;
  float* hkT    = hqT + (size_t)N_ * H_ * KQ_ * T_;
  float* out_ws = hkT + (size_t)N_ * H_ * KQ_ * T_;

  hipLaunchKernelGGL(proj_kernel, dim3(256), dim3(256), 0, stream,
                     query, key, Wq, bq, Wk, bk, hqT, hkT);
  hipLaunchKernelGGL(attn_kernel, dim3(8192), dim3(64), 0, stream,
                     hqT, hkT, mask, value, p_out, out_ws);
  hipLaunchKernelGGL(outproj_kernel, dim3(512), dim3(256), 0, stream,
                     out_ws, Wo, bo, out_rep);
}

// Round 20
// 158.594 us; speedup vs baseline: 1.7700x; 1.0295x over previous
//
#include <hip/hip_runtime.h>

// Problem constants: N=8, T=256, H=8, KQ=128, V=32
#define N_ 8
#define T_ 256
#define H_ 8
#define KQ_ 128
#define V_ 32

typedef float f32x4 __attribute__((ext_vector_type(4)));

// ---------------------------------------------------------------------------
// Phase 1 v5 (frozen from R12): tiled-GEMM projections, dst[n][h][d][t].
// grid: 256 = proj(2)*n(8)*h(8)*dh(2), 256 thr
// ---------------------------------------------------------------------------
__global__ __launch_bounds__(256) void proj_kernel(
    const float* __restrict__ query, const float* __restrict__ key,
    const float* __restrict__ Wq, const float* __restrict__ bq,
    const float* __restrict__ Wk, const float* __restrict__ bk,
    float* __restrict__ hqT, float* __restrict__ hkT)
{
  int b = blockIdx.x;
  int dh = b & 1;
  int h  = (b >> 1) & 7;
  int n  = (b >> 4) & 7;
  int proj = (b >> 7) & 1;
  const float* src  = proj ? key : query;
  const float* W    = proj ? Wk  : Wq;
  const float* bias = proj ? bk  : bq;
  float* dst        = proj ? hkT : hqT;
  int d0 = dh * 64;

  __shared__ float qs[256 * 36];
  __shared__ float ws[64 * 36];

  int tl   = threadIdx.x & 31;
  int dsub = threadIdx.x >> 5;
  const float* qsrc = src + (size_t)n * T_ * KQ_;
  const float* wsrc = W + (size_t)(h * KQ_ + d0) * KQ_;

  float acc[8][8];
#pragma unroll
  for (int it = 0; it < 8; ++it)
#pragma unroll
    for (int dd = 0; dd < 8; ++dd) acc[it][dd] = 0.f;

  for (int kc = 0; kc < 4; ++kc) {
    if (kc) __syncthreads();
    {
      int r = threadIdx.x >> 3, c4 = (threadIdx.x & 7) * 4;
#pragma unroll
      for (int rep = 0; rep < 8; ++rep) {
        int row = r + rep * 32;
        *(float4*)&qs[row * 36 + c4] =
            *(const float4*)&qsrc[(size_t)row * KQ_ + kc * 32 + c4];
      }
#pragma unroll
      for (int rep = 0; rep < 2; ++rep) {
        int row = r + rep * 32;
        *(float4*)&ws[row * 36 + c4] =
            *(const float4*)&wsrc[(size_t)row * KQ_ + kc * 32 + c4];
      }
    }
    __syncthreads();

#pragma unroll 2
    for (int j0 = 0; j0 < 32; j0 += 4) {
      float4 qv[8];
#pragma unroll
      for (int it = 0; it < 8; ++it)
        qv[it] = *(const float4*)&qs[(tl + 32 * it) * 36 + j0];
#pragma unroll
      for (int dd = 0; dd < 8; ++dd) {
        float4 w4 = *(const float4*)&ws[(dsub * 8 + dd) * 36 + j0];
#pragma unroll
        for (int it = 0; it < 8; ++it) {
          acc[it][dd] = fmaf(qv[it].x, w4.x, acc[it][dd]);
          acc[it][dd] = fmaf(qv[it].y, w4.y, acc[it][dd]);
          acc[it][dd] = fmaf(qv[it].z, w4.z, acc[it][dd]);
          acc[it][dd] = fmaf(qv[it].w, w4.w, acc[it][dd]);
        }
      }
    }
  }

#pragma unroll
  for (int dd = 0; dd < 8; ++dd) {
    int d = d0 + dsub * 8 + dd;
    float bb = bias[h * KQ_ + d];
    size_t base = (((size_t)n * H_ + h) * KQ_ + d) * T_;
#pragma unroll
    for (int it = 0; it < 8; ++it)
      dst[base + it * 32 + tl] = acc[it][dd] + bb;
  }
}

// ---------------------------------------------------------------------------
// Phase 2 FUSED v3 (R20): v1's 8-q tile + 128 threads (2 waves)/block.
// R16: v1 (64thr) = 123us; R19: v2 (2q tiles) = ~128us REGRESSION (all
// blocks co-resident, no stagger; 4x denom per-q cost). v3 keeps v1's
// per-q efficiency, halves each serial phase, 2x waves/SIMD (2->4):
// wave w owns k-half. Same instruction totals as v1.
// grid: 2048 = n(8)*h(8)*qtile(32 of 8q), 128 threads, ~19KB LDS.
// ---------------------------------------------------------------------------
__global__ __launch_bounds__(128) void attn_kernel(
    const float* __restrict__ hqT, const float* __restrict__ hkT,
    const int* __restrict__ mask, const float* __restrict__ value,
    float* __restrict__ p_out, float* __restrict__ out_ws)
{
  const float SCALE = 0.08838834764831845f;   // 1/sqrt(128)
  int b = blockIdx.x;
  int q0 = (b & 31) * 8;
  int h  = (b >> 5) & 7;
  int n  = b >> 8;
  int t  = threadIdx.x;                        // 0..127 (2 waves)
  int w  = t >> 6;                             // wave id
  int row0 = (n * H_ + h) * T_ + q0;

  __shared__ float hq_s[KQ_ * 12];   // [j][qq] pad 12 -> 6.1KB
  __shared__ float e_s[T_ * 8];      // [k][qq] 8KB
  __shared__ float inv_s[8 * 32];    // [qq][v] 1KB
  __shared__ float wred[2 * 8];      // per-wave max partials
  __shared__ float red_s[8 * 32];    // cross-wave denom partials 1KB
  __shared__ float red_o[8 * 32];    // 1KB

  const float* hqbase = hqT + ((size_t)n * H_ + h) * KQ_ * T_;
  const float* hkbase = hkT + ((size_t)n * H_ + h) * KQ_ * T_;

  // stage hq: 128j x 8q, 8 elems/thread
#pragma unroll
  for (int rep = 0; rep < 8; ++rep) {
    int i = t + 128 * rep;
    int j = i >> 3, qq = i & 7;
    hq_s[j * 12 + qq] = hqbase[(size_t)j * T_ + q0 + qq];
  }
  __syncthreads();

  // scores: thread t covers k = t and k = t+128 (2 k's)
  float acc[2][8];
#pragma unroll
  for (int i = 0; i < 2; ++i)
#pragma unroll
    for (int qq = 0; qq < 8; ++qq) acc[i][qq] = 0.f;

#pragma unroll 4
  for (int j = 0; j < KQ_; ++j) {
    float hk0 = hkbase[(size_t)j * T_ + t];
    float hk1 = hkbase[(size_t)j * T_ + t + 128];
    float4 a0 = *(const float4*)&hq_s[j * 12];       // wave-uniform broadcast
    float4 a1 = *(const float4*)&hq_s[j * 12 + 4];
    acc[0][0] = fmaf(a0.x, hk0, acc[0][0]); acc[0][1] = fmaf(a0.y, hk0, acc[0][1]);
    acc[0][2] = fmaf(a0.z, hk0, acc[0][2]); acc[0][3] = fmaf(a0.w, hk0, acc[0][3]);
    acc[0][4] = fmaf(a1.x, hk0, acc[0][4]); acc[0][5] = fmaf(a1.y, hk0, acc[0][5]);
    acc[0][6] = fmaf(a1.z, hk0, acc[0][6]); acc[0][7] = fmaf(a1.w, hk0, acc[0][7]);
    acc[1][0] = fmaf(a0.x, hk1, acc[1][0]); acc[1][1] = fmaf(a0.y, hk1, acc[1][1]);
    acc[1][2] = fmaf(a0.z, hk1, acc[1][2]); acc[1][3] = fmaf(a0.w, hk1, acc[1][3]);
    acc[1][4] = fmaf(a1.x, hk1, acc[1][4]); acc[1][5] = fmaf(a1.y, hk1, acc[1][5]);
    acc[1][6] = fmaf(a1.z, hk1, acc[1][6]); acc[1][7] = fmaf(a1.w, hk1, acc[1][7]);
  }

  // max over k: per-wave shfl reduce, then cross-wave via LDS
  float mloc[8];
#pragma unroll
  for (int qq = 0; qq < 8; ++qq) {
    float m = fmaxf(acc[0][qq], acc[1][qq]) * SCALE;
    for (int off = 32; off >= 1; off >>= 1)
      m = fmaxf(m, __shfl_xor(m, off, 64));
    mloc[qq] = m;
  }
  if ((t & 63) == 0) {
#pragma unroll
    for (int qq = 0; qq < 8; ++qq) wred[w * 8 + qq] = mloc[qq];
  }
  __syncthreads();
  {
#pragma unroll
    for (int qq = 0; qq < 8; ++qq) {
      float mx = fmaxf(wred[qq], wred[8 + qq]);
      acc[0][qq] = __expf(acc[0][qq] * SCALE - mx);
      acc[1][qq] = __expf(acc[1][qq] * SCALE - mx);
    }
    *(f32x4*)&e_s[t * 8]           = f32x4{acc[0][0], acc[0][1], acc[0][2], acc[0][3]};
    *(f32x4*)&e_s[t * 8 + 4]       = f32x4{acc[0][4], acc[0][5], acc[0][6], acc[0][7]};
    *(f32x4*)&e_s[(t + 128) * 8]     = f32x4{acc[1][0], acc[1][1], acc[1][2], acc[1][3]};
    *(f32x4*)&e_s[(t + 128) * 8 + 4] = f32x4{acc[1][4], acc[1][5], acc[1][6], acc[1][7]};
  }
  __syncthreads();

  // denominators + PV: v = t&31, kg = t>>5 (4 groups of 64 k's)
  const int*   mrow = mask  + (size_t)n * T_ * V_;
  const float* vrow = value + (size_t)n * T_ * V_;
  int v = t & 31, kg = t >> 5;
  float s8[8], o8[8];
#pragma unroll
  for (int qq = 0; qq < 8; ++qq) { s8[qq] = 0.f; o8[qq] = 0.f; }
#pragma unroll 4
  for (int i = 0; i < 64; ++i) {
    int k = kg * 64 + i;
    float mf = (float)mrow[k * V_ + v];
    float vv = vrow[k * V_ + v];
    float4 e0 = *(const float4*)&e_s[k * 8];
    float4 e1 = *(const float4*)&e_s[k * 8 + 4];
    float p;
    p = e0.x * mf; s8[0] += p; o8[0] = fmaf(p, vv, o8[0]);
    p = e0.y * mf; s8[1] += p; o8[1] = fmaf(p, vv, o8[1]);
    p = e0.z * mf; s8[2] += p; o8[2] = fmaf(p, vv, o8[2]);
    p = e0.w * mf; s8[3] += p; o8[3] = fmaf(p, vv, o8[3]);
    p = e1.x * mf; s8[4] += p; o8[4] = fmaf(p, vv, o8[4]);
    p = e1.y * mf; s8[5] += p; o8[5] = fmaf(p, vv, o8[5]);
    p = e1.z * mf; s8[6] += p; o8[6] = fmaf(p, vv, o8[6]);
    p = e1.w * mf; s8[7] += p; o8[7] = fmaf(p, vv, o8[7]);
  }
  // pair-reduce kg within wave (t <-> t^32: same v, partner kg)
#pragma unroll
  for (int qq = 0; qq < 8; ++qq) {
    s8[qq] += __shfl_xor(s8[qq], 32, 64);
    o8[qq] += __shfl_xor(o8[qq], 32, 64);
  }
  if (w == 1 && (t & 63) < 32) {
#pragma unroll
    for (int qq = 0; qq < 8; ++qq) {
      red_s[qq * 32 + v] = s8[qq];
      red_o[qq * 32 + v] = o8[qq];
    }
  }
  __syncthreads();
  if (w == 0 && (t & 63) < 32) {
#pragma unroll
    for (int qq = 0; qq < 8; ++qq) {
      float s = s8[qq] + red_s[qq * 32 + v];
      float o = o8[qq] + red_o[qq * 32 + v];
      float inv = 1.0f / s;
      inv_s[qq * 32 + v] = inv;
      out_ws[(((size_t)n * T_ + q0 + qq) * H_ + h) * V_ + v] = o * inv;
    }
  }
  __syncthreads();

  // direct p_attn streaming: 8 rows x 2048 f32x4 split over 128 thr
  {
    int v0 = (t & 7) * 4;
    f32x4 iv[8];
#pragma unroll
    for (int qq = 0; qq < 8; ++qq)
      iv[qq] = *(const f32x4*)&inv_s[qq * 32 + v0];
    f32x4* pbase = (f32x4*)p_out + (size_t)row0 * 2048;

#pragma unroll 4
    for (int rep = 0; rep < 16; ++rep) {
      int e4 = rep * 128 + t;
      int k  = rep * 16 + (t >> 3);
      const int4 m4 = *(const int4*)&mrow[k * V_ + v0];
      float fx = (float)m4.x, fy = (float)m4.y, fz = (float)m4.z, fw = (float)m4.w;
      f32x4 e0 = *(const f32x4*)&e_s[k * 8];
      f32x4 e1 = *(const f32x4*)&e_s[k * 8 + 4];
      float e[8] = {e0.x, e0.y, e0.z, e0.w, e1.x, e1.y, e1.z, e1.w};
#pragma unroll
      for (int qq = 0; qq < 8; ++qq) {
        f32x4 pv;
        pv.x = e[qq] * fx * iv[qq].x;
        pv.y = e[qq] * fy * iv[qq].y;
        pv.z = e[qq] * fz * iv[qq].z;
        pv.w = e[qq] * fw * iv[qq].w;
        __builtin_nontemporal_store(pv, &pbase[(size_t)qq * 2048 + e4]);
      }
    }
  }
}

// ---------------------------------------------------------------------------
// Phase 3 v2 (frozen from R8)
// ---------------------------------------------------------------------------
__global__ __launch_bounds__(256) void outproj_kernel(
    const float* __restrict__ out_ws, const float* __restrict__ Wo,
    const float* __restrict__ bo, float* __restrict__ out_rep)
{
  __shared__ float wot[256 * 33];
  __shared__ float rows_s[4 * 256];
  __shared__ float red[4 * 32];
  int r0 = blockIdx.x * 4;
  for (int i = threadIdx.x; i < 32 * 256; i += 256) {
    int o = i >> 8, c = i & 255;
    wot[c * 33 + o] = Wo[i];
  }
  for (int i = threadIdx.x; i < 4 * 256; i += 256)
    rows_s[i] = out_ws[(size_t)r0 * 256 + i];
  __syncthreads();
  int o  = threadIdx.x & 31;
  int rr = (threadIdx.x >> 5) & 3;
  int kh = threadIdx.x >> 7;
  int cb = kh * 128;
  float acc = 0.f;
#pragma unroll 4
  for (int c = 0; c < 128; ++c)
    acc = fmaf(rows_s[rr * 256 + cb + c], wot[(cb + c) * 33 + o], acc);
  if (kh == 1) red[rr * 32 + o] = acc;
  __syncthreads();
  if (kh == 0)
    out_rep[(size_t)(r0 + rr) * 32 + o] = acc + red[rr * 32 + o] + bo[o];
}

// ---------------------------------------------------------------------------
extern "C" void kernel_launch(void* const* d_in, const int* in_sizes, int n_in,
                              void* d_out, int out_size, void* d_ws, size_t ws_size,
                              hipStream_t stream) {
  const float* value = (const float*)d_in[0];
  const float* key   = (const float*)d_in[1];
  const float* query = (const float*)d_in[2];
  const int*   mask  = (const int*)d_in[3];
  const float* Wq = (const float*)d_in[4];
  const float* bq = (const float*)d_in[5];
  const float* Wk = (const float*)d_in[6];
  const float* bk = (const float*)d_in[7];
  const float* Wo = (const float*)d_in[8];
  const float* bo = (const float*)d_in[9];

  float* out_rep = (float*)d_out;
  float* p_out   = (float*)d_out + (size_t)N_ * T_ * V_;

  float* hqT    = (float*)d_ws;
  float* hkT    = hqT + (size_t)N_ * H_ * KQ_ * T_;
  float* out_ws = hkT + (size_t)N_ * H_ * KQ_ * T_;

  hipLaunchKernelGGL(proj_kernel, dim3(256), dim3(256), 0, stream,
                     query, key, Wq, bq, Wk, bk, hqT, hkT);
  hipLaunchKernelGGL(attn_kernel, dim3(2048), dim3(128), 0, stream,
                     hqT, hkT, mask, value, p_out, out_ws);
  hipLaunchKernelGGL(outproj_kernel, dim3(512), dim3(256), 0, stream,
                     out_ws, Wo, bo, out_rep);
}

// Round 21
// 148.125 us; speedup vs baseline: 1.8951x; 1.0707x over previous
//
#include <hip/hip_runtime.h>

// Problem constants: N=8, T=256, H=8, KQ=128, V=32
#define N_ 8
#define T_ 256
#define H_ 8
#define KQ_ 128
#define V_ 32
#define QT_ 8
#define EPAD 9   // e_s leading dim: coprime to 32 banks

typedef float f32x4 __attribute__((ext_vector_type(4)));

// ---------------------------------------------------------------------------
// Phase 1 v5 (frozen from R12): tiled-GEMM projections, dst[n][h][d][t].
// grid: 256 = proj(2)*n(8)*h(8)*dh(2), 256 thr
// ---------------------------------------------------------------------------
__global__ __launch_bounds__(256) void proj_kernel(
    const float* __restrict__ query, const float* __restrict__ key,
    const float* __restrict__ Wq, const float* __restrict__ bq,
    const float* __restrict__ Wk, const float* __restrict__ bk,
    float* __restrict__ hqT, float* __restrict__ hkT)
{
  int b = blockIdx.x;
  int dh = b & 1;
  int h  = (b >> 1) & 7;
  int n  = (b >> 4) & 7;
  int proj = (b >> 7) & 1;
  const float* src  = proj ? key : query;
  const float* W    = proj ? Wk  : Wq;
  const float* bias = proj ? bk  : bq;
  float* dst        = proj ? hkT : hqT;
  int d0 = dh * 64;

  __shared__ float qs[256 * 36];
  __shared__ float ws[64 * 36];

  int tl   = threadIdx.x & 31;
  int dsub = threadIdx.x >> 5;
  const float* qsrc = src + (size_t)n * T_ * KQ_;
  const float* wsrc = W + (size_t)(h * KQ_ + d0) * KQ_;

  float acc[8][8];
#pragma unroll
  for (int it = 0; it < 8; ++it)
#pragma unroll
    for (int dd = 0; dd < 8; ++dd) acc[it][dd] = 0.f;

  for (int kc = 0; kc < 4; ++kc) {
    if (kc) __syncthreads();
    {
      int r = threadIdx.x >> 3, c4 = (threadIdx.x & 7) * 4;
#pragma unroll
      for (int rep = 0; rep < 8; ++rep) {
        int row = r + rep * 32;
        *(float4*)&qs[row * 36 + c4] =
            *(const float4*)&qsrc[(size_t)row * KQ_ + kc * 32 + c4];
      }
#pragma unroll
      for (int rep = 0; rep < 2; ++rep) {
        int row = r + rep * 32;
        *(float4*)&ws[row * 36 + c4] =
            *(const float4*)&wsrc[(size_t)row * KQ_ + kc * 32 + c4];
      }
    }
    __syncthreads();

#pragma unroll 2
    for (int j0 = 0; j0 < 32; j0 += 4) {
      float4 qv[8];
#pragma unroll
      for (int it = 0; it < 8; ++it)
        qv[it] = *(const float4*)&qs[(tl + 32 * it) * 36 + j0];
#pragma unroll
      for (int dd = 0; dd < 8; ++dd) {
        float4 w4 = *(const float4*)&ws[(dsub * 8 + dd) * 36 + j0];
#pragma unroll
        for (int it = 0; it < 8; ++it) {
          acc[it][dd] = fmaf(qv[it].x, w4.x, acc[it][dd]);
          acc[it][dd] = fmaf(qv[it].y, w4.y, acc[it][dd]);
          acc[it][dd] = fmaf(qv[it].z, w4.z, acc[it][dd]);
          acc[it][dd] = fmaf(qv[it].w, w4.w, acc[it][dd]);
        }
      }
    }
  }

#pragma unroll
  for (int dd = 0; dd < 8; ++dd) {
    int d = d0 + dsub * 8 + dd;
    float bb = bias[h * KQ_ + d];
    size_t base = (((size_t)n * H_ + h) * KQ_ + d) * T_;
#pragma unroll
    for (int it = 0; it < 8; ++it)
      dst[base + it * 32 + tl] = acc[it][dd] + bb;
  }
}

// ---------------------------------------------------------------------------
// Phase 2 FUSED v4 (R21): the MEASURED-38us R8 attn (256 thr, 8q, EPAD e_s,
// kg-split denominator) + direct NT p_attn streaming. The previously-fused
// 64/128-thr variants (123us) descended from an unmeasured regressed rewrite.
// LDS 30.5KB -> 5 blocks/CU (20 waves).
// grid: 2048 = n(8)*h(8)*qtile(32 of 8q), 256 threads.
// ---------------------------------------------------------------------------
__global__ __launch_bounds__(256) void attn_kernel(
    const float* __restrict__ hqT, const float* __restrict__ hkT,
    const int* __restrict__ mask, const float* __restrict__ value,
    float* __restrict__ p_out, float* __restrict__ out_ws)
{
  const float SCALE = 0.08838834764831845f;   // 1/sqrt(128)
  int b = blockIdx.x;
  int q0 = (b & 31) * QT_;
  int h  = (b >> 5) & 7;
  int n  = b >> 8;
  int t  = threadIdx.x;
  int row0 = (n * H_ + h) * T_ + q0;

  __shared__ float hq_s[KQ_ * 8];      // 4KB
  __shared__ float e_s[T_ * EPAD];     // 9.2KB
  __shared__ float wred[4 * 8];
  __shared__ float red_s[8 * 8 * 32];  // 8KB
  __shared__ float red_o[8 * 8 * 32];  // 8KB
  __shared__ float inv_s[8 * 32];      // 1KB

  const float* hqbase = hqT + ((size_t)n * H_ + h) * KQ_ * T_;
  const float* hkbase = hkT + ((size_t)n * H_ + h) * KQ_ * T_;

  {
    int qq = t & 7, j0 = t >> 3;
#pragma unroll
    for (int rep = 0; rep < 4; ++rep) {
      int j = j0 + rep * 32;
      hq_s[j * 8 + qq] = hqbase[(size_t)j * T_ + q0 + qq];
    }
  }
  __syncthreads();

  // scores: thread t = k
  float acc[8];
#pragma unroll
  for (int qq = 0; qq < 8; ++qq) acc[qq] = 0.f;
#pragma unroll 4
  for (int j = 0; j < KQ_; ++j) {
    float hk = hkbase[(size_t)j * T_ + t];
    float4 a0 = *(const float4*)&hq_s[j * 8];
    float4 a1 = *(const float4*)&hq_s[j * 8 + 4];
    acc[0] = fmaf(a0.x, hk, acc[0]);
    acc[1] = fmaf(a0.y, hk, acc[1]);
    acc[2] = fmaf(a0.z, hk, acc[2]);
    acc[3] = fmaf(a0.w, hk, acc[3]);
    acc[4] = fmaf(a1.x, hk, acc[4]);
    acc[5] = fmaf(a1.y, hk, acc[5]);
    acc[6] = fmaf(a1.z, hk, acc[6]);
    acc[7] = fmaf(a1.w, hk, acc[7]);
  }
#pragma unroll
  for (int qq = 0; qq < 8; ++qq) acc[qq] *= SCALE;

  // max over k: wave shfl reduce + cross-wave LDS
  float mloc[8];
#pragma unroll
  for (int qq = 0; qq < 8; ++qq) {
    float m = acc[qq];
    for (int off = 32; off >= 1; off >>= 1)
      m = fmaxf(m, __shfl_xor(m, off, 64));
    mloc[qq] = m;
  }
  if ((t & 63) == 0) {
    int w = t >> 6;
#pragma unroll
    for (int qq = 0; qq < 8; ++qq) wred[w * 8 + qq] = mloc[qq];
  }
  __syncthreads();
  {
    float ev[8];
#pragma unroll
    for (int qq = 0; qq < 8; ++qq) {
      float mx = fmaxf(fmaxf(wred[0*8+qq], wred[1*8+qq]),
                       fmaxf(wred[2*8+qq], wred[3*8+qq]));
      ev[qq] = __expf(acc[qq] - mx);
    }
    *(float4*)&e_s[t * EPAD]     = make_float4(ev[0], ev[1], ev[2], ev[3]);
    *(float4*)&e_s[t * EPAD + 4] = make_float4(ev[4], ev[5], ev[6], ev[7]);
  }
  __syncthreads();

  // denominators + PV: thread = (kg = t>>5, v = t&31)
  const int*   mrow = mask  + (size_t)n * T_ * V_;
  const float* vrow = value + (size_t)n * T_ * V_;
  int v = t & 31, kg = t >> 5;
  float s8[8], o8[8];
#pragma unroll
  for (int qq = 0; qq < 8; ++qq) { s8[qq] = 0.f; o8[qq] = 0.f; }
  for (int i = 0; i < 32; ++i) {
    int k = kg * 32 + i;
    float mf = (float)mrow[k * V_ + v];
    float vv = vrow[k * V_ + v];
    float4 e0 = *(const float4*)&e_s[k * EPAD];
    float4 e1 = *(const float4*)&e_s[k * EPAD + 4];
    float p;
    p = e0.x * mf; s8[0] += p; o8[0] = fmaf(p, vv, o8[0]);
    p = e0.y * mf; s8[1] += p; o8[1] = fmaf(p, vv, o8[1]);
    p = e0.z * mf; s8[2] += p; o8[2] = fmaf(p, vv, o8[2]);
    p = e0.w * mf; s8[3] += p; o8[3] = fmaf(p, vv, o8[3]);
    p = e1.x * mf; s8[4] += p; o8[4] = fmaf(p, vv, o8[4]);
    p = e1.y * mf; s8[5] += p; o8[5] = fmaf(p, vv, o8[5]);
    p = e1.z * mf; s8[6] += p; o8[6] = fmaf(p, vv, o8[6]);
    p = e1.w * mf; s8[7] += p; o8[7] = fmaf(p, vv, o8[7]);
  }
#pragma unroll
  for (int qq = 0; qq < 8; ++qq) {
    red_s[(kg * 8 + qq) * 32 + v] = s8[qq];
    red_o[(kg * 8 + qq) * 32 + v] = o8[qq];
  }
  __syncthreads();
  {
    int qq = t >> 5, v2 = t & 31;
    float s = 0.f, o = 0.f;
#pragma unroll
    for (int kg2 = 0; kg2 < 8; ++kg2) {
      s += red_s[(kg2 * 8 + qq) * 32 + v2];
      o += red_o[(kg2 * 8 + qq) * 32 + v2];
    }
    float inv = 1.0f / s;
    inv_s[qq * 32 + v2] = inv;
    out_ws[(((size_t)n * T_ + q0 + qq) * H_ + h) * V_ + v2] = o * inv;
  }
  __syncthreads();

  // direct p_attn streaming: 8 rows x 2048 f32x4 over 256 thr, NT coalesced
  {
    int v0 = (t & 7) * 4;
    f32x4 iv[8];
#pragma unroll
    for (int qq = 0; qq < 8; ++qq)
      iv[qq] = *(const f32x4*)&inv_s[qq * 32 + v0];
    f32x4* pbase = (f32x4*)p_out + (size_t)row0 * 2048;

#pragma unroll
    for (int rep = 0; rep < 8; ++rep) {
      int e4 = rep * 256 + t;
      int k  = rep * 32 + (t >> 3);
      const int4 m4 = *(const int4*)&mrow[k * V_ + v0];
      float fx = (float)m4.x, fy = (float)m4.y, fz = (float)m4.z, fw = (float)m4.w;
      f32x4 e0 = *(const f32x4*)&e_s[k * EPAD];
      f32x4 e1 = *(const f32x4*)&e_s[k * EPAD + 4];
      float e[8] = {e0.x, e0.y, e0.z, e0.w, e1.x, e1.y, e1.z, e1.w};
#pragma unroll
      for (int qq = 0; qq < 8; ++qq) {
        f32x4 pv;
        pv.x = e[qq] * fx * iv[qq].x;
        pv.y = e[qq] * fy * iv[qq].y;
        pv.z = e[qq] * fz * iv[qq].z;
        pv.w = e[qq] * fw * iv[qq].w;
        __builtin_nontemporal_store(pv, &pbase[(size_t)qq * 2048 + e4]);
      }
    }
  }
}

// ---------------------------------------------------------------------------
// Phase 3 v2 (frozen from R8)
// ---------------------------------------------------------------------------
__global__ __launch_bounds__(256) void outproj_kernel(
    const float* __restrict__ out_ws, const float* __restrict__ Wo,
    const float* __restrict__ bo, float* __restrict__ out_rep)
{
  __shared__ float wot[256 * 33];
  __shared__ float rows_s[4 * 256];
  __shared__ float red[4 * 32];
  int r0 = blockIdx.x * 4;
  for (int i = threadIdx.x; i < 32 * 256; i += 256) {
    int o = i >> 8, c = i & 255;
    wot[c * 33 + o] = Wo[i];
  }
  for (int i = threadIdx.x; i < 4 * 256; i += 256)
    rows_s[i] = out_ws[(size_t)r0 * 256 + i];
  __syncthreads();
  int o  = threadIdx.x & 31;
  int rr = (threadIdx.x >> 5) & 3;
  int kh = threadIdx.x >> 7;
  int cb = kh * 128;
  float acc = 0.f;
#pragma unroll 4
  for (int c = 0; c < 128; ++c)
    acc = fmaf(rows_s[rr * 256 + cb + c], wot[(cb + c) * 33 + o], acc);
  if (kh == 1) red[rr * 32 + o] = acc;
  __syncthreads();
  if (kh == 0)
    out_rep[(size_t)(r0 + rr) * 32 + o] = acc + red[rr * 32 + o] + bo[o];
}

// ---------------------------------------------------------------------------
extern "C" void kernel_launch(void* const* d_in, const int* in_sizes, int n_in,
                              void* d_out, int out_size, void* d_ws, size_t ws_size,
                              hipStream_t stream) {
  const float* value = (const float*)d_in[0];
  const float* key   = (const float*)d_in[1];
  const float* query = (const float*)d_in[2];
  const int*   mask  = (const int*)d_in[3];
  const float* Wq = (const float*)d_in[4];
  const float* bq = (const float*)d_in[5];
  const float* Wk = (const float*)d_in[6];
  const float* bk = (const float*)d_in[7];
  const float* Wo = (const float*)d_in[8];
  const float* bo = (const float*)d_in[9];

  float* out_rep = (float*)d_out;
  float* p_out   = (float*)d_out + (size_t)N_ * T_ * V_;

  float* hqT    = (float*)d_ws;
  float* hkT    = hqT + (size_t)N_ * H_ * KQ_ * T_;
  float* out_ws = hkT + (size_t)N_ * H_ * KQ_ * T_;

  hipLaunchKernelGGL(proj_kernel, dim3(256), dim3(256), 0, stream,
                     query, key, Wq, bq, Wk, bk, hqT, hkT);
  hipLaunchKernelGGL(attn_kernel, dim3(2048), dim3(256), 0, stream,
                     hqT, hkT, mask, value, p_out, out_ws);
  hipLaunchKernelGGL(outproj_kernel, dim3(512), dim3(256), 0, stream,
                     out_ws, Wo, bo, out_rep);
}